// Round 11
// baseline (188.532 us; speedup 1.0000x reference)
//
#include <hip/hip_runtime.h>

// CrossWarpingModule: 4-phase pixel-unshuffle -> axial attention (8 heads, c=1)
// -> flow -> bilinear border grid_sample -> pixel-shuffle back.
// B=2, C=64, H=W=256; sub-images: 8 x [64][128][128].
//
// R18 = R8/R15 config (session best, 166.9us) with prep_w DELETED.
// qkv reads Wq/Wk/Wv directly on the scalar path: indices i*64+(c0+c) are
// wave-uniform (readfirstlane'd c0, unrolled i/c) -> s_load from the
// 768-float constant-cache-resident tables. LOG2E fold moved to a uniform
// per-channel multiply (same fp32 op prep_w performed -> bit-identical).
// One fewer dispatch + one fewer inter-dispatch gap.
// R17's qkv+attnH fusion reverted: measured 41.96us = sum of phases, not
// max (2 blocks/CU, barrier lock-step killed the overlap).

constexpr int PLANE = 16384;                 // 128*128
constexpr float LOG2E = 1.4426950408889634f;

typedef float v2f __attribute__((ext_vector_type(2)));

// Packed fp32 helpers. Accumulating forms tie dest=src to save VGPRs.
static __device__ __forceinline__ v2f pk_mul(v2f a, v2f b) {
    v2f d;
    asm("v_pk_mul_f32 %0, %1, %2" : "=v"(d) : "v"(a), "v"(b));
    return d;
}
static __device__ __forceinline__ void pk_addi(v2f& d, v2f a) {
    asm("v_pk_add_f32 %0, %0, %1" : "+v"(d) : "v"(a));
}
static __device__ __forceinline__ void pk_fmai(v2f& d, v2f a, v2f b) {
    asm("v_pk_fma_f32 %0, %1, %2, %0" : "+v"(d) : "v"(a), "v"(b));
}

// ---------------------------------------------------------------------------
// Kernel 1: q/k/v projection. Block = (b, Y, X-half): 128 contiguous X
// positions x 4 channel-groups (16 ch each). Tree-reduce in LDS.
// Weights via scalar path directly from Wq/Wk/Wv (uniform indices).
// K written pre-scaled by log2(e) (weight scaled before fma, = R15 bits).
// grid 1024 x 512.
// ---------------------------------------------------------------------------
__global__ __launch_bounds__(512) void qkv_kernel(
    const float* __restrict__ cur, const float* __restrict__ ref,
    const float* __restrict__ Wq, const float* __restrict__ Wk,
    const float* __restrict__ Wv,
    float* __restrict__ Q, float* __restrict__ K, float* __restrict__ V)
{
    __shared__ float red0[128 * 25];    // stride 25: conflict-free
    __shared__ float red1[128 * 25];
    const int tid = threadIdx.x;

    const int bi = blockIdx.x;               // 0..1023
    const int b  = bi >> 9;                  // batch
    const int Y  = (bi >> 1) & 255;          // full-res row
    const int Xh = bi & 1;                   // X half
    const int cg = tid >> 7;                 // channel group 0..3 (wave-uniform)
    const int xi = tid & 127;
    const int X  = Xh * 128 + xi;            // full-res col (contiguous/lane)

    const size_t base_in = (size_t)b * 64 * 65536 + (size_t)Y * 256 + X;
    const float* curp = cur + base_in;
    const float* refp = ref + base_in;

    float q[8], k[8], v[8];
#pragma unroll
    for (int i = 0; i < 8; ++i) { q[i] = 0.f; k[i] = 0.f; v[i] = 0.f; }

    // c0 wave-uniform -> weight reads select the scalar path (s_load,
    // 768 floats constant-cache resident).
    const int c0 = __builtin_amdgcn_readfirstlane(cg * 16);
#pragma unroll 8
    for (int c = 0; c < 16; ++c) {
        const int cc = c0 + c;
        float cu = curp[(size_t)cc * 65536];
        float rf = refp[(size_t)cc * 65536];
#pragma unroll
        for (int i = 0; i < 8; ++i) {
            const float wq = Wq[i * 64 + cc];
            const float wk = LOG2E * Wk[i * 64 + cc];   // same op prep_w did
            const float wv_ = Wv[i * 64 + cc];
            q[i] = fmaf(wq,  cu, q[i]);
            k[i] = fmaf(wk,  rf, k[i]);
            v[i] = fmaf(wv_, rf, v[i]);
        }
    }

    // tree reduce: (1 -> red0), (3 -> red1); (2 += red1); (0 += red0);
    // final store adds red1.
    float* row0 = &red0[xi * 25];
    float* row1 = &red1[xi * 25];
    if (cg == 1) {
#pragma unroll
        for (int i = 0; i < 8; ++i) {
            row0[i] = q[i]; row0[8 + i] = k[i]; row0[16 + i] = v[i];
        }
    } else if (cg == 3) {
#pragma unroll
        for (int i = 0; i < 8; ++i) {
            row1[i] = q[i]; row1[8 + i] = k[i]; row1[16 + i] = v[i];
        }
    }
    __syncthreads();
    if (cg == 2) {
#pragma unroll
        for (int i = 0; i < 8; ++i) {
            row1[i]      += q[i];
            row1[8 + i]  += k[i];
            row1[16 + i] += v[i];
        }
    } else if (cg == 0) {
#pragma unroll
        for (int i = 0; i < 8; ++i) {
            q[i] += row0[i]; k[i] += row0[8 + i]; v[i] += row0[16 + i];
        }
    }
    __syncthreads();
    if (cg == 0) {
        const int dy = Y & 1, dx = X & 1;
        // (dy,dx)->phase: (0,0)=0 (1,1)=1 (0,1)=2 (1,0)=3
        const int p  = dy ? (dx ? 1 : 3) : (dx ? 2 : 0);
        const int sb = p * 2 + b;
        const int h = Y >> 1, w = X >> 1;
#pragma unroll
        for (int i = 0; i < 8; ++i) {
            const size_t o = ((size_t)(sb * 8 + i) << 14) + (h << 7) + w;
            Q[o] = q[i] + row1[i];
            K[o] = k[i] + row1[8 + i];
            V[o] = v[i] + row1[16 + i];
        }
    }
}

// ---------------------------------------------------------------------------
// Kernel 2: both axial attention passes + 8->1 head projection, fused.
// Block = (pass, sb, line), 256 threads = 4 waves.
// Wave wv owns heads {2wv, 2wv+1}; lane owns outputs {lane, lane+64}.
// Wave-PRIVATE staging + s_waitcnt lgkmcnt(0) (no staging barrier).
// Per l: 12 pk + 8 exp, mov-free operands. Epilogue: 4-wave partial sum.
// Pass-1 block IDs encoded as P = (w>>4) + 8*sb + 64*(w&15) -> same XCD
// for the 16 blocks sharing each 64B line-group. grid 2048 x 256.
// ---------------------------------------------------------------------------
__global__ __launch_bounds__(256) void attn_fused(
    const float* __restrict__ Q, const float* __restrict__ K,
    const float* __restrict__ V,
    const float* __restrict__ Whor, const float* __restrict__ Wver,
    float* __restrict__ OH, float* __restrict__ OVT)
{
    __shared__ __align__(16) float kk[4][2 * 132];  // per-wave: 2 heads, 132-pad
    __shared__ __align__(16) float vv[4][2 * 132];
    __shared__ float part[4 * 128];                 // per-wave partial sums

    const int pass = blockIdx.x >> 10;
    const int P    = blockIdx.x & 1023;
    int sb, line;
    if (!pass) {
        sb   = P >> 7;
        line = P & 127;
    } else {
        // P = (w>>4) + 8*sb + 64*(w&15)  (bijective over [0,1024))
        const int w4 = P & 7, wl = P >> 6;
        sb   = (P >> 3) & 7;
        line = (w4 << 4) | wl;                    // w
    }
    const float* __restrict__ wsel = pass ? Wver : Whor;
    float* __restrict__ o = pass ? OVT : OH;

    const int tid  = threadIdx.x;
    const int wv   = tid >> 6;          // wave 0..3 -> heads {2wv, 2wv+1}
    const int lane = tid & 63;
    const size_t sbb = ((size_t)(sb * 8)) << 14;  // base of sb's 8 planes

    // per-lane Q base offsets for its two outputs:
    size_t qb0, qb1;
    if (!pass) {
        qb0 = sbb + ((size_t)line << 7) + lane;
        qb1 = qb0 + 64;
    } else {
        qb0 = sbb + ((size_t)lane << 7) + line;
        qb1 = qb0 + ((size_t)64 << 7);
    }

    // prefetch Q (4 scalars) alongside staging
    float qv00, qv01, qv10, qv11;
    {
        const int h0 = 2 * wv, h1 = 2 * wv + 1;
        qv00 = Q[qb0 + ((size_t)h0 << 14)];
        qv01 = Q[qb1 + ((size_t)h0 << 14)];
        qv10 = Q[qb0 + ((size_t)h1 << 14)];
        qv11 = Q[qb1 + ((size_t)h1 << 14)];
    }

    // ---- wave-private staging: this wave's 2 heads x 128 elems each ----
    {
        const int hl = lane >> 5;                 // local head 0/1
        const int hh = 2 * wv + hl;               // global head
        const int fi = lane & 31;                 // quad id within head
        float* kd = &kk[wv][hl * 132 + (fi << 2)];
        float* vd = &vv[wv][hl * 132 + (fi << 2)];
        if (!pass) {
            const size_t g = sbb + ((size_t)hh << 14) + ((size_t)line << 7) + (fi << 2);
            *(float4*)kd = *(const float4*)&K[g];
            *(float4*)vd = *(const float4*)&V[g];
        } else {
            // column `line`: rows fi*4 .. fi*4+3 of head hh
            const size_t g = sbb + ((size_t)hh << 14) + ((size_t)(fi << 2) << 7) + line;
            float4 kq, vq;
            kq.x = K[g];       kq.y = K[g + 128];
            kq.z = K[g + 256]; kq.w = K[g + 384];
            vq.x = V[g];       vq.y = V[g + 128];
            vq.z = V[g + 256]; vq.w = V[g + 384];
            *(float4*)kd = kq;
            *(float4*)vd = vq;
        }
    }
    // wave-internal fence: ds_writes retired; wave64 lockstep makes all
    // lanes' writes visible to all lanes without a workgroup barrier.
    asm volatile("s_waitcnt lgkmcnt(0)" ::: "memory");

    float acc0 = 0.f, acc1 = 0.f;
#pragma unroll
    for (int i = 0; i < 2; ++i) {
        const int head = 2 * wv + i;              // wave-uniform
        const float q0 = i ? qv10 : qv00;
        const float q1 = i ? qv11 : qv01;
        const v2f s0 = { q0, q0 };                // built once per head
        const v2f s1 = { q1, q1 };
        const float4* k4 = (const float4*)&kk[wv][i * 132];
        const float4* v4 = (const float4*)&vv[wv][i * 132];
        v2f dA0 = {0.f, 0.f}, dB0 = {0.f, 0.f};
        v2f nA0 = {0.f, 0.f}, nB0 = {0.f, 0.f};
        v2f dA1 = {0.f, 0.f}, dB1 = {0.f, 0.f};
        v2f nA1 = {0.f, 0.f}, nB1 = {0.f, 0.f};
#pragma unroll 8
        for (int l = 0; l < 32; ++l) {
            const float4 kq = k4[l];
            const float4 vq = v4[l];
            const v2f k01 = { kq.x, kq.y }, k23 = { kq.z, kq.w };   // subregs
            const v2f v01 = { vq.x, vq.y }, v23 = { vq.z, vq.w };
            // output w0
            const v2f a0 = pk_mul(s0, k01);
            const v2f b0 = pk_mul(s0, k23);
            const v2f e0 = { __builtin_amdgcn_exp2f(a0.x), __builtin_amdgcn_exp2f(a0.y) };
            const v2f f0 = { __builtin_amdgcn_exp2f(b0.x), __builtin_amdgcn_exp2f(b0.y) };
            pk_addi(dA0, e0);
            pk_addi(dB0, f0);
            pk_fmai(nA0, e0, v01);
            pk_fmai(nB0, f0, v23);
            // output w1
            const v2f a1 = pk_mul(s1, k01);
            const v2f b1 = pk_mul(s1, k23);
            const v2f e1 = { __builtin_amdgcn_exp2f(a1.x), __builtin_amdgcn_exp2f(a1.y) };
            const v2f f1 = { __builtin_amdgcn_exp2f(b1.x), __builtin_amdgcn_exp2f(b1.y) };
            pk_addi(dA1, e1);
            pk_addi(dB1, f1);
            pk_fmai(nA1, e1, v01);
            pk_fmai(nB1, f1, v23);
        }
        const float wh = wsel[head];
        pk_addi(dA0, dB0); pk_addi(nA0, nB0);
        pk_addi(dA1, dB1); pk_addi(nA1, nB1);
        acc0 = fmaf(wh, (nA0.x + nA0.y) * __builtin_amdgcn_rcpf(dA0.x + dA0.y), acc0);
        acc1 = fmaf(wh, (nA1.x + nA1.y) * __builtin_amdgcn_rcpf(dA1.x + dA1.y), acc1);
    }

    // 4-wave partial-sum epilogue (single barrier in the kernel)
    part[wv * 128 + lane]      = acc0;
    part[wv * 128 + lane + 64] = acc1;
    __syncthreads();
    if (tid < 128) {
        const float s = (part[tid] + part[256 + tid])
                      + (part[128 + tid] + part[384 + tid]);
        o[((size_t)sb << 14) + ((size_t)line << 7) + tid] = s;
    }
}

// ---------------------------------------------------------------------------
// Kernel 3: warp, output-major. Block = (b, cgroup, Y); lane = X. Stores are
// contiguous full-res rows. Both x-taps (cols 2*x0c+dx, 2*x1c+dx) fetched as
// ONE float4 per row at col base cb=min(2*x0c,252) -> 2 dwordx4 per channel
// instead of 4 scalar loads; taps picked with cndmask (hi/up1 select covers
// border clamp). grid 2048 x 256.
// ---------------------------------------------------------------------------
__global__ __launch_bounds__(256) void warp_kernel(
    const float* __restrict__ ref, const float* __restrict__ ovt,
    const float* __restrict__ oh, float* __restrict__ out)
{
    const int bi = blockIdx.x;          // 0..2047
    const int Y  = bi & 255;
    const int cg = (bi >> 8) & 3;
    const int b  = bi >> 10;
    const int X  = threadIdx.x;

    const int dy = Y & 1, dx = X & 1;
    const int p  = dy ? (dx ? 1 : 3) : (dx ? 2 : 0);
    const int sb = p * 2 + b;
    const int h = Y >> 1, w = X >> 1;

    // normalized-coord round trip cancels exactly:
    const float ix = (float)w + oh [((size_t)sb << 14) + (h << 7) + w];
    const float iy = (float)h + ovt[((size_t)sb << 14) + (w << 7) + h];

    const float x0f = floorf(ix), y0f = floorf(iy);
    const float wx = ix - x0f,    wy = iy - y0f;
    const int x0 = (int)x0f, y0 = (int)y0f;
    const int x0c = min(max(x0, 0), 127),     x1c = min(max(x0 + 1, 0), 127);
    const int y0c = min(max(y0, 0), 127),     y1c = min(max(y0 + 1, 0), 127);

    const float w00 = (1.f - wx) * (1.f - wy);
    const float w01 = wx * (1.f - wy);
    const float w10 = (1.f - wx) * wy;
    const float w11 = wx * wy;

    const int cb  = min(2 * x0c, 252);      // float4 col base (8B-aligned ok)
    const bool hi  = (x0c == 127);          // taps live in upper half of f4
    const bool up1 = hi | (x1c != x0c);     // second tap uses upper element
    const int r0 = (2 * y0c + dy) * 256, r1 = (2 * y1c + dy) * 256;
    const int dst = Y * 256 + X;

    const float* rp = ref + ((size_t)b * 64 + cg * 16) * 65536;
    float* op = out + ((size_t)b * 64 + cg * 16) * 65536;

#pragma unroll 4
    for (int c = 0; c < 16; ++c) {
        const size_t pl = (size_t)c * 65536;
        const float4 f0 = *(const float4*)&rp[pl + r0 + cb];
        const float4 f1 = *(const float4*)&rp[pl + r1 + cb];
        const float L0 = dx ? f0.y : f0.x, H0 = dx ? f0.w : f0.z;
        const float L1 = dx ? f1.y : f1.x, H1 = dx ? f1.w : f1.z;
        const float v00 = hi ? H0 : L0,  v01 = up1 ? H0 : L0;
        const float v10 = hi ? H1 : L1,  v11 = up1 ? H1 : L1;
        op[pl + dst] = fmaf(w00, v00, fmaf(w01, v01, fmaf(w10, v10, w11 * v11)));
    }
}

// ---------------------------------------------------------------------------
extern "C" void kernel_launch(void* const* d_in, const int* in_sizes, int n_in,
                              void* d_out, int out_size, void* d_ws, size_t ws_size,
                              hipStream_t stream)
{
    const float* cur  = (const float*)d_in[0];
    const float* ref  = (const float*)d_in[1];
    const float* Wq   = (const float*)d_in[2];
    const float* Wk   = (const float*)d_in[3];
    const float* Wv   = (const float*)d_in[4];
    const float* Wver = (const float*)d_in[5];
    const float* Whor = (const float*)d_in[6];
    float* out = (float*)d_out;

    float* ws = (float*)d_ws;
    const size_t NQ = 8 * 8 * (size_t)PLANE;   // 1,048,576 floats
    float* Q   = ws;
    float* K   = Q  + NQ;                      // pre-scaled by log2(e)
    float* V   = K  + NQ;
    float* OVT = V  + NQ;                      // [sb][w][h]
    float* OH  = OVT + 8 * (size_t)PLANE;      // [sb][h][w]

    qkv_kernel<<<1024, 512, 0, stream>>>(cur, ref, Wq, Wk, Wv, Q, K, V);
    attn_fused<<<2048, 256, 0, stream>>>(Q, K, V, Whor, Wver, OH, OVT);
    warp_kernel<<<2048, 256, 0, stream>>>(ref, OVT, OH, out);
}

// Round 12
// 166.191 us; speedup vs baseline: 1.1344x; 1.1344x over previous
//
#include <hip/hip_runtime.h>

// CrossWarpingModule: 4-phase pixel-unshuffle -> axial attention (8 heads, c=1)
// -> flow -> bilinear border grid_sample -> pixel-shuffle back.
// B=2, C=64, H=W=256; sub-images: 8 x [64][128][128].
//
// R19 = exact revert to R15 (session best, 166.9us).
// R18's lesson: the WTg prep table is LOAD-BEARING -- its contiguous
// [c][24] rows are what let the compiler promote weight reads to the
// scalar path (s_load of whole rows). Direct Wq/Wk/Wv reads (stride-64,
// 3 tables) demoted to per-lane VMEM: qkv 24 -> 58.7us (VALUBusy 46%,
// ~27us of addressing/load overhead vs 2.6us of real fma demand).
// R16 (float2 qkv loads) and R17 (qkv+attnH fusion) also measured
// negative: qkv is latency/occupancy-bound; barrier'd fusion serializes.
// Structure: prep_w (WTg, Wk pre-scaled by log2e) -> qkv (scalar-path
// weights, stride-25 LDS tree) -> attn_fused (wave-private staging, no
// staging barrier, mov-free pk/exp inner loop) -> warp (float4 tap pairs).

constexpr int PLANE = 16384;                 // 128*128
constexpr float LOG2E = 1.4426950408889634f;

typedef float v2f __attribute__((ext_vector_type(2)));

// Packed fp32 helpers. Accumulating forms tie dest=src to save VGPRs.
static __device__ __forceinline__ v2f pk_mul(v2f a, v2f b) {
    v2f d;
    asm("v_pk_mul_f32 %0, %1, %2" : "=v"(d) : "v"(a), "v"(b));
    return d;
}
static __device__ __forceinline__ void pk_addi(v2f& d, v2f a) {
    asm("v_pk_add_f32 %0, %0, %1" : "+v"(d) : "v"(a));
}
static __device__ __forceinline__ void pk_fmai(v2f& d, v2f a, v2f b) {
    asm("v_pk_fma_f32 %0, %1, %2, %0" : "+v"(d) : "v"(a), "v"(b));
}

// ---------------------------------------------------------------------------
// Kernel 0: weight prep. WTg[c*24+j]: j<8 Wq, <16 Wk*log2e, <24 Wv.
// One tiny block; ~1-2us. The contiguous per-channel rows enable the
// scalar path in qkv (do not delete -- see R18 regression).
// ---------------------------------------------------------------------------
__global__ __launch_bounds__(64) void prep_w(
    const float* __restrict__ Wq, const float* __restrict__ Wk,
    const float* __restrict__ Wv, float* __restrict__ WTg)
{
    const int c = threadIdx.x;               // 0..63
#pragma unroll
    for (int j = 0; j < 8; ++j) {
        WTg[c * 24 + j]      = Wq[j * 64 + c];
        WTg[c * 24 + 8 + j]  = LOG2E * Wk[j * 64 + c];
        WTg[c * 24 + 16 + j] = Wv[j * 64 + c];
    }
}

// ---------------------------------------------------------------------------
// Kernel 1: q/k/v projection. Block = (b, Y, X-half): 128 contiguous X
// positions x 4 channel-groups (16 ch each). Tree-reduce in LDS.
// Weights come from WTg via the scalar path (uniform index).
// grid 1024 x 512.
// ---------------------------------------------------------------------------
__global__ __launch_bounds__(512) void qkv_kernel(
    const float* __restrict__ cur, const float* __restrict__ ref,
    const float* __restrict__ WTg,
    float* __restrict__ Q, float* __restrict__ K, float* __restrict__ V)
{
    __shared__ float red0[128 * 25];    // stride 25: conflict-free
    __shared__ float red1[128 * 25];
    const int tid = threadIdx.x;

    const int bi = blockIdx.x;               // 0..1023
    const int b  = bi >> 9;                  // batch
    const int Y  = (bi >> 1) & 255;          // full-res row
    const int Xh = bi & 1;                   // X half
    const int cg = tid >> 7;                 // channel group 0..3 (wave-uniform)
    const int xi = tid & 127;
    const int X  = Xh * 128 + xi;            // full-res col (contiguous/lane)

    const size_t base_in = (size_t)b * 64 * 65536 + (size_t)Y * 256 + X;
    const float* curp = cur + base_in;
    const float* refp = ref + base_in;

    float q[8], k[8], v[8];
#pragma unroll
    for (int i = 0; i < 8; ++i) { q[i] = 0.f; k[i] = 0.f; v[i] = 0.f; }

    // c0 is wave-uniform; readfirstlane makes it compiler-provably scalar
    // so WTg reads select the SMEM path (s_load, constant-cache resident).
    const int c0 = __builtin_amdgcn_readfirstlane(cg * 16);
#pragma unroll 8
    for (int c = 0; c < 16; ++c) {
        float cu = curp[(size_t)(c0 + c) * 65536];
        float rf = refp[(size_t)(c0 + c) * 65536];
        const float* wr = &WTg[(c0 + c) * 24];
#pragma unroll
        for (int i = 0; i < 8; ++i) {
            q[i] = fmaf(wr[i],      cu, q[i]);
            k[i] = fmaf(wr[8 + i],  rf, k[i]);
            v[i] = fmaf(wr[16 + i], rf, v[i]);
        }
    }

    // tree reduce: (1 -> red0), (3 -> red1); (2 += red1); (0 += red0);
    // final store adds red1.
    float* row0 = &red0[xi * 25];
    float* row1 = &red1[xi * 25];
    if (cg == 1) {
#pragma unroll
        for (int i = 0; i < 8; ++i) {
            row0[i] = q[i]; row0[8 + i] = k[i]; row0[16 + i] = v[i];
        }
    } else if (cg == 3) {
#pragma unroll
        for (int i = 0; i < 8; ++i) {
            row1[i] = q[i]; row1[8 + i] = k[i]; row1[16 + i] = v[i];
        }
    }
    __syncthreads();
    if (cg == 2) {
#pragma unroll
        for (int i = 0; i < 8; ++i) {
            row1[i]      += q[i];
            row1[8 + i]  += k[i];
            row1[16 + i] += v[i];
        }
    } else if (cg == 0) {
#pragma unroll
        for (int i = 0; i < 8; ++i) {
            q[i] += row0[i]; k[i] += row0[8 + i]; v[i] += row0[16 + i];
        }
    }
    __syncthreads();
    if (cg == 0) {
        const int dy = Y & 1, dx = X & 1;
        // (dy,dx)->phase: (0,0)=0 (1,1)=1 (0,1)=2 (1,0)=3
        const int p  = dy ? (dx ? 1 : 3) : (dx ? 2 : 0);
        const int sb = p * 2 + b;
        const int h = Y >> 1, w = X >> 1;
#pragma unroll
        for (int i = 0; i < 8; ++i) {
            const size_t o = ((size_t)(sb * 8 + i) << 14) + (h << 7) + w;
            Q[o] = q[i] + row1[i];
            K[o] = k[i] + row1[8 + i];
            V[o] = v[i] + row1[16 + i];
        }
    }
}

// ---------------------------------------------------------------------------
// Kernel 2: both axial attention passes + 8->1 head projection, fused.
// Block = (pass, sb, line), 256 threads = 4 waves.
// Wave wv owns heads {2wv, 2wv+1}; lane owns outputs {lane, lane+64}.
// Wave-PRIVATE staging + s_waitcnt lgkmcnt(0) (no staging barrier).
// Per l: 12 pk + 8 exp, mov-free operands. Epilogue: 4-wave partial sum.
// Pass-1 block IDs encoded as P = (w>>4) + 8*sb + 64*(w&15) -> same XCD
// for the 16 blocks sharing each 64B line-group. grid 2048 x 256.
// ---------------------------------------------------------------------------
__global__ __launch_bounds__(256) void attn_fused(
    const float* __restrict__ Q, const float* __restrict__ K,
    const float* __restrict__ V,
    const float* __restrict__ Whor, const float* __restrict__ Wver,
    float* __restrict__ OH, float* __restrict__ OVT)
{
    __shared__ __align__(16) float kk[4][2 * 132];  // per-wave: 2 heads, 132-pad
    __shared__ __align__(16) float vv[4][2 * 132];
    __shared__ float part[4 * 128];                 // per-wave partial sums

    const int pass = blockIdx.x >> 10;
    const int P    = blockIdx.x & 1023;
    int sb, line;
    if (!pass) {
        sb   = P >> 7;
        line = P & 127;
    } else {
        // P = (w>>4) + 8*sb + 64*(w&15)  (bijective over [0,1024))
        const int w4 = P & 7, wl = P >> 6;
        sb   = (P >> 3) & 7;
        line = (w4 << 4) | wl;                    // w
    }
    const float* __restrict__ wsel = pass ? Wver : Whor;
    float* __restrict__ o = pass ? OVT : OH;

    const int tid  = threadIdx.x;
    const int wv   = tid >> 6;          // wave 0..3 -> heads {2wv, 2wv+1}
    const int lane = tid & 63;
    const size_t sbb = ((size_t)(sb * 8)) << 14;  // base of sb's 8 planes

    // per-lane Q base offsets for its two outputs:
    size_t qb0, qb1;
    if (!pass) {
        qb0 = sbb + ((size_t)line << 7) + lane;
        qb1 = qb0 + 64;
    } else {
        qb0 = sbb + ((size_t)lane << 7) + line;
        qb1 = qb0 + ((size_t)64 << 7);
    }

    // prefetch Q (4 scalars) alongside staging
    float qv00, qv01, qv10, qv11;
    {
        const int h0 = 2 * wv, h1 = 2 * wv + 1;
        qv00 = Q[qb0 + ((size_t)h0 << 14)];
        qv01 = Q[qb1 + ((size_t)h0 << 14)];
        qv10 = Q[qb0 + ((size_t)h1 << 14)];
        qv11 = Q[qb1 + ((size_t)h1 << 14)];
    }

    // ---- wave-private staging: this wave's 2 heads x 128 elems each ----
    {
        const int hl = lane >> 5;                 // local head 0/1
        const int hh = 2 * wv + hl;               // global head
        const int fi = lane & 31;                 // quad id within head
        float* kd = &kk[wv][hl * 132 + (fi << 2)];
        float* vd = &vv[wv][hl * 132 + (fi << 2)];
        if (!pass) {
            const size_t g = sbb + ((size_t)hh << 14) + ((size_t)line << 7) + (fi << 2);
            *(float4*)kd = *(const float4*)&K[g];
            *(float4*)vd = *(const float4*)&V[g];
        } else {
            // column `line`: rows fi*4 .. fi*4+3 of head hh
            const size_t g = sbb + ((size_t)hh << 14) + ((size_t)(fi << 2) << 7) + line;
            float4 kq, vq;
            kq.x = K[g];       kq.y = K[g + 128];
            kq.z = K[g + 256]; kq.w = K[g + 384];
            vq.x = V[g];       vq.y = V[g + 128];
            vq.z = V[g + 256]; vq.w = V[g + 384];
            *(float4*)kd = kq;
            *(float4*)vd = vq;
        }
    }
    // wave-internal fence: ds_writes retired; wave64 lockstep makes all
    // lanes' writes visible to all lanes without a workgroup barrier.
    asm volatile("s_waitcnt lgkmcnt(0)" ::: "memory");

    float acc0 = 0.f, acc1 = 0.f;
#pragma unroll
    for (int i = 0; i < 2; ++i) {
        const int head = 2 * wv + i;              // wave-uniform
        const float q0 = i ? qv10 : qv00;
        const float q1 = i ? qv11 : qv01;
        const v2f s0 = { q0, q0 };                // built once per head
        const v2f s1 = { q1, q1 };
        const float4* k4 = (const float4*)&kk[wv][i * 132];
        const float4* v4 = (const float4*)&vv[wv][i * 132];
        v2f dA0 = {0.f, 0.f}, dB0 = {0.f, 0.f};
        v2f nA0 = {0.f, 0.f}, nB0 = {0.f, 0.f};
        v2f dA1 = {0.f, 0.f}, dB1 = {0.f, 0.f};
        v2f nA1 = {0.f, 0.f}, nB1 = {0.f, 0.f};
#pragma unroll 8
        for (int l = 0; l < 32; ++l) {
            const float4 kq = k4[l];
            const float4 vq = v4[l];
            const v2f k01 = { kq.x, kq.y }, k23 = { kq.z, kq.w };   // subregs
            const v2f v01 = { vq.x, vq.y }, v23 = { vq.z, vq.w };
            // output w0
            const v2f a0 = pk_mul(s0, k01);
            const v2f b0 = pk_mul(s0, k23);
            const v2f e0 = { __builtin_amdgcn_exp2f(a0.x), __builtin_amdgcn_exp2f(a0.y) };
            const v2f f0 = { __builtin_amdgcn_exp2f(b0.x), __builtin_amdgcn_exp2f(b0.y) };
            pk_addi(dA0, e0);
            pk_addi(dB0, f0);
            pk_fmai(nA0, e0, v01);
            pk_fmai(nB0, f0, v23);
            // output w1
            const v2f a1 = pk_mul(s1, k01);
            const v2f b1 = pk_mul(s1, k23);
            const v2f e1 = { __builtin_amdgcn_exp2f(a1.x), __builtin_amdgcn_exp2f(a1.y) };
            const v2f f1 = { __builtin_amdgcn_exp2f(b1.x), __builtin_amdgcn_exp2f(b1.y) };
            pk_addi(dA1, e1);
            pk_addi(dB1, f1);
            pk_fmai(nA1, e1, v01);
            pk_fmai(nB1, f1, v23);
        }
        const float wh = wsel[head];
        pk_addi(dA0, dB0); pk_addi(nA0, nB0);
        pk_addi(dA1, dB1); pk_addi(nA1, nB1);
        acc0 = fmaf(wh, (nA0.x + nA0.y) * __builtin_amdgcn_rcpf(dA0.x + dA0.y), acc0);
        acc1 = fmaf(wh, (nA1.x + nA1.y) * __builtin_amdgcn_rcpf(dA1.x + dA1.y), acc1);
    }

    // 4-wave partial-sum epilogue (single barrier in the kernel)
    part[wv * 128 + lane]      = acc0;
    part[wv * 128 + lane + 64] = acc1;
    __syncthreads();
    if (tid < 128) {
        const float s = (part[tid] + part[256 + tid])
                      + (part[128 + tid] + part[384 + tid]);
        o[((size_t)sb << 14) + ((size_t)line << 7) + tid] = s;
    }
}

// ---------------------------------------------------------------------------
// Kernel 3: warp, output-major. Block = (b, cgroup, Y); lane = X. Stores are
// contiguous full-res rows. Both x-taps (cols 2*x0c+dx, 2*x1c+dx) fetched as
// ONE float4 per row at col base cb=min(2*x0c,252) -> 2 dwordx4 per channel
// instead of 4 scalar loads; taps picked with cndmask (hi/up1 select covers
// border clamp). grid 2048 x 256.
// ---------------------------------------------------------------------------
__global__ __launch_bounds__(256) void warp_kernel(
    const float* __restrict__ ref, const float* __restrict__ ovt,
    const float* __restrict__ oh, float* __restrict__ out)
{
    const int bi = blockIdx.x;          // 0..2047
    const int Y  = bi & 255;
    const int cg = (bi >> 8) & 3;
    const int b  = bi >> 10;
    const int X  = threadIdx.x;

    const int dy = Y & 1, dx = X & 1;
    const int p  = dy ? (dx ? 1 : 3) : (dx ? 2 : 0);
    const int sb = p * 2 + b;
    const int h = Y >> 1, w = X >> 1;

    // normalized-coord round trip cancels exactly:
    const float ix = (float)w + oh [((size_t)sb << 14) + (h << 7) + w];
    const float iy = (float)h + ovt[((size_t)sb << 14) + (w << 7) + h];

    const float x0f = floorf(ix), y0f = floorf(iy);
    const float wx = ix - x0f,    wy = iy - y0f;
    const int x0 = (int)x0f, y0 = (int)y0f;
    const int x0c = min(max(x0, 0), 127),     x1c = min(max(x0 + 1, 0), 127);
    const int y0c = min(max(y0, 0), 127),     y1c = min(max(y0 + 1, 0), 127);

    const float w00 = (1.f - wx) * (1.f - wy);
    const float w01 = wx * (1.f - wy);
    const float w10 = (1.f - wx) * wy;
    const float w11 = wx * wy;

    const int cb  = min(2 * x0c, 252);      // float4 col base (8B-aligned ok)
    const bool hi  = (x0c == 127);          // taps live in upper half of f4
    const bool up1 = hi | (x1c != x0c);     // second tap uses upper element
    const int r0 = (2 * y0c + dy) * 256, r1 = (2 * y1c + dy) * 256;
    const int dst = Y * 256 + X;

    const float* rp = ref + ((size_t)b * 64 + cg * 16) * 65536;
    float* op = out + ((size_t)b * 64 + cg * 16) * 65536;

#pragma unroll 4
    for (int c = 0; c < 16; ++c) {
        const size_t pl = (size_t)c * 65536;
        const float4 f0 = *(const float4*)&rp[pl + r0 + cb];
        const float4 f1 = *(const float4*)&rp[pl + r1 + cb];
        const float L0 = dx ? f0.y : f0.x, H0 = dx ? f0.w : f0.z;
        const float L1 = dx ? f1.y : f1.x, H1 = dx ? f1.w : f1.z;
        const float v00 = hi ? H0 : L0,  v01 = up1 ? H0 : L0;
        const float v10 = hi ? H1 : L1,  v11 = up1 ? H1 : L1;
        op[pl + dst] = fmaf(w00, v00, fmaf(w01, v01, fmaf(w10, v10, w11 * v11)));
    }
}

// ---------------------------------------------------------------------------
extern "C" void kernel_launch(void* const* d_in, const int* in_sizes, int n_in,
                              void* d_out, int out_size, void* d_ws, size_t ws_size,
                              hipStream_t stream)
{
    const float* cur  = (const float*)d_in[0];
    const float* ref  = (const float*)d_in[1];
    const float* Wq   = (const float*)d_in[2];
    const float* Wk   = (const float*)d_in[3];
    const float* Wv   = (const float*)d_in[4];
    const float* Wver = (const float*)d_in[5];
    const float* Whor = (const float*)d_in[6];
    float* out = (float*)d_out;

    float* ws = (float*)d_ws;
    const size_t NQ = 8 * 8 * (size_t)PLANE;   // 1,048,576 floats
    float* Q   = ws;
    float* K   = Q  + NQ;                      // pre-scaled by log2(e)
    float* V   = K  + NQ;
    float* OVT = V  + NQ;                      // [sb][w][h]
    float* OH  = OVT + 8 * (size_t)PLANE;      // [sb][h][w]
    float* WTg = OH  + 8 * (size_t)PLANE;      // 64*24 transposed weights

    prep_w<<<1, 64, 0, stream>>>(Wq, Wk, Wv, WTg);
    qkv_kernel<<<1024, 512, 0, stream>>>(cur, ref, WTg, Q, K, V);
    attn_fused<<<2048, 256, 0, stream>>>(Q, K, V, Whor, Wver, OH, OVT);
    warp_kernel<<<2048, 256, 0, stream>>>(ref, OVT, OH, out);
}